// Round 3
// baseline (2516.542 us; speedup 1.0000x reference)
//
#include <hip/hip_runtime.h>
#include <cmath>

#define TPB    256
#define SWEEPS 6
#define NTRI   2080      // 64*65/2
#define LDW    68        // row stride (floats): 16B-aligned rows, verified in R6

typedef float v4f __attribute__((ext_vector_type(4)));

// 21 XOR-closed triples {b1, b2, b1^b2} covering masks 1..63 — verified R6.
__constant__ int TB1[21] = {58,53,41,17,34,32,13,26,52,43,37,35,18,36,20,40,44,38,54,47,33};
__constant__ int TH1[21] = { 5, 5, 5, 4, 5, 5, 3, 4, 5, 5, 5, 5, 4, 5, 4, 5, 5, 5, 5, 5, 5};
__constant__ int TB2[21] = { 1, 2, 4, 8,16, 7, 3, 6,12,24,21, 9, 5,10,11,22,19,27,15,30,29};
__constant__ int TH2[21] = { 0, 1, 2, 3, 4, 2, 1, 2, 3, 4, 4, 3, 2, 3, 3, 4, 4, 4, 3, 4, 4};

__device__ __forceinline__ int rfl(int x) { return __builtin_amdgcn_readfirstlane(x); }

template<int CTRL>
__device__ __forceinline__ float dppf(float x) {
    return __int_as_float(__builtin_amdgcn_update_dpp(0, __float_as_int(x), CTRL, 0xf, 0xf, true));
}
// sum across 16-lane DPP row, broadcast to all 16 lanes (verified R6)
__device__ __forceinline__ float red16(float x) {
    x += dppf<0x124>(x);   // row_ror:4
    x += dppf<0x128>(x);   // row_ror:8
    x += dppf<0xB1>(x);    // quad_perm [1,0,3,2]
    x += dppf<0x4E>(x);    // quad_perm [2,3,0,1]
    return x;
}

#if __has_builtin(__builtin_elementwise_fma)
__device__ __forceinline__ v4f v4fma(v4f a, v4f b, v4f c) { return __builtin_elementwise_fma(a, b, c); }
#else
__device__ __forceinline__ v4f v4fma(v4f a, v4f b, v4f c) {
    v4f r; r.x=fmaf(a.x,b.x,c.x); r.y=fmaf(a.y,b.y,c.y); r.z=fmaf(a.z,b.z,c.z); r.w=fmaf(a.w,b.w,c.w); return r;
}
#endif

// fma-chain dot of two v4f (1 mul + 3 fma instead of 4 mul + 3 add) — R8
__device__ __forceinline__ float dot4(v4f a, v4f b) {
    float d = a.x * b.x;
    d = fmaf(a.y, b.y, d);
    d = fmaf(a.z, b.z, d);
    d = fmaf(a.w, b.w, d);
    return d;
}

// One Jacobi rotation on register-resident W rows (no VT). Angle math = R4/R6 verified.
// R9: sqrtf -> __builtin_amdgcn_sqrtf (single v_sqrt_f32 in the serial angle chain).
__device__ __forceinline__ void jrot2(v4f& wp, v4f& wq, float& np, float& nq) {
    float apq = red16(dot4(wp, wq));
    float tau = (nq - np) * 0.5f * __builtin_amdgcn_rcpf(apq);
    float den = fabsf(tau) + __builtin_amdgcn_sqrtf(fmaf(tau, tau, 1.f));
    float tt  = copysignf(__builtin_amdgcn_rcpf(den), tau);
    tt = (fabsf(apq) < 1e-30f) ? 0.f : tt;
    float c = __builtin_amdgcn_rsqf(fmaf(tt, tt, 1.f));
    float s = tt * c;
    v4f cc = {c,c,c,c}, ss = {s,s,s,s};
    v4f wa = wp;
    wp = v4fma(cc, wp, -(ss * wq));   // c*wp - s*wq
    wq = v4fma(cc, wq,  (ss * wa));   // c*wq + s*wa
    np = fmaf(-tt, apq, np);
    nq = fmaf( tt, apq, nq);
}

__global__ __launch_bounds__(TPB, 6) void spd_logm_kernel(const float* __restrict__ in,
                                                          float* __restrict__ out) {
    // LDS: Wb 17408 B + Ltri 8320 B + norms 256 B + rs 256 B ~= 26.2 KB -> 6 blocks/CU
    __shared__ __align__(16) float Wb[64 * LDW];
    __shared__ __align__(16) float Ltri[NTRI];        // L, row-major lower-tri: [r*(r+1)/2 + c]
    __shared__ __align__(16) float norms[64];         // rsq(diag) -> row norm^2 -> log(lambda)
    __shared__ __align__(16) float rs[64];            // 1/L[j][j] for deferred back-sub scale

    const int b    = blockIdx.x;
    const int t    = threadIdx.x;
    const int lane = t & 63;
    const int w    = rfl(t >> 6);   // wave id (SGPR)
    const int G    = t >> 4;        // 16-lane group 0..15 (one 4-row coset)
    const int u    = t & 15;
    const int u4   = u << 2;

    // ---- load A (b128) ----
    const float4* __restrict__ in4 = (const float4*)(in + (size_t)b * 4096);
    for (int e = t; e < 1024; e += TPB) {
        int row = e >> 4, col = (e & 15) << 2;
        *(float4*)&Wb[row * LDW + col] = in4[e];
    }
    __syncthreads();

    // ---- Cholesky, LDL-style (deferred column scaling): 1 barrier per k  (R8) ----
    // Trailing update W[i][j] -= W[i][k] * (W[j][k] / d_k) uses the RAW column k,
    // which nobody writes during iteration k -> no pre-barrier needed.
    for (int k = 0; k < 64; ++k) {
        float dk  = Wb[k * LDW + k];                 // lane-uniform LDS broadcast
        float rdk = __builtin_amdgcn_rcpf(dk);
        float ck  = Wb[lane * LDW + k];              // raw column k
        float ckp = ck * rdk;                        // W[lane][k] / d_k
        for (int i = k + 1 + w; i < 64; i += 4) {
            float aik = __shfl(ck, i, 64);           // W[i][k] raw (uniform idx -> broadcast)
            if (lane > k) Wb[i * LDW + lane] = fmaf(-aik, ckp, Wb[i * LDW + lane]);
        }
        __syncthreads();
    }
    // deferred scaling: L[i][k] = W[i][k] * rsq(d_k); diag -> sqrt(d_k).
    if (t < 64) norms[t] = __builtin_amdgcn_rsqf(Wb[t * LDW + t]);
    __syncthreads();
    for (int e = t; e < 4096; e += TPB) {              // zero strict upper (writes c>r only)
        int r = e >> 6, c = e & 63;
        if (c > r) Wb[r * LDW + c] = 0.f;
    }
    for (int e = t; e < NTRI; e += TPB) {              // scale lower in place + compact copy
        int r = (int)((sqrtf(fmaf(8.f, (float)e, 1.f)) - 1.f) * 0.5f);
        while (r > 0 && r * (r + 1) / 2 > e) --r;
        while ((r + 1) * (r + 2) / 2 <= e) ++r;
        int c = e - r * (r + 1) / 2;
        float v = Wb[r * LDW + c] * norms[c];          // unique (r,c) per e -> race-free
        Wb[r * LDW + c] = v;
        Ltri[e] = v;
    }
    __syncthreads();

    // ---- one-sided Jacobi on rows of L (no VT accumulation) ----
    for (int sweep = 0; sweep < SWEEPS; ++sweep) {
        #pragma unroll
        for (int i = 0; i < 4; ++i) {                  // exact norm^2 refresh
            int r = ((t >> 4) << 2) + i;
            v4f x = *(v4f*)&Wb[r * LDW + u4];
            float nn = red16(dot4(x, x));
            if (u == 0) norms[r] = nn;
        }
        __syncthreads();

        for (int j = 0; j < 21; ++j) {
            const int b1 = TB1[j], h1 = TH1[j], b2 = TB2[j], h2 = TH2[j];
            int m  = (G & ((1 << h2) - 1)) | ((G >> h2) << (h2 + 1));
            int rp = (m & ((1 << h1) - 1)) | ((m >> h1) << (h1 + 1));
            const int z0 = rp, z1 = rp ^ b1, z2 = rp ^ b2, z3 = z1 ^ b2;

            v4f w0 = *(v4f*)&Wb[z0 * LDW + u4];
            v4f w1 = *(v4f*)&Wb[z1 * LDW + u4];
            v4f w2 = *(v4f*)&Wb[z2 * LDW + u4];
            v4f w3 = *(v4f*)&Wb[z3 * LDW + u4];
            float n0 = norms[z0], n1 = norms[z1], n2 = norms[z2], n3 = norms[z3];

            jrot2(w0, w1, n0, n1);  jrot2(w2, w3, n2, n3);
            jrot2(w0, w2, n0, n2);  jrot2(w1, w3, n1, n3);
            jrot2(w0, w3, n0, n3);  jrot2(w1, w2, n1, n2);

            *(v4f*)&Wb[z0 * LDW + u4] = w0;
            *(v4f*)&Wb[z1 * LDW + u4] = w1;
            *(v4f*)&Wb[z2 * LDW + u4] = w2;
            *(v4f*)&Wb[z3 * LDW + u4] = w3;
            if (u == 0) { norms[z0] = n0; norms[z1] = n1; norms[z2] = n2; norms[z3] = n3; }
            __syncthreads();
        }
    }

    // ---- eigenvalues: lambda_k = ||row k||^2 (exact), store log ----
    #pragma unroll
    for (int i = 0; i < 4; ++i) {
        int r = ((t >> 4) << 2) + i;
        v4f x = *(v4f*)&Wb[r * LDW + u4];
        float nn = red16(dot4(x, x));
        if (u == 0) norms[r] = logf(nn);
    }
    __syncthreads();

    // ---- transpose Wb in place (RHS of the solve) + precompute rs[j] = 1/L[j][j] ----
    if (t < 64) rs[t] = __builtin_amdgcn_rcpf(Ltri[(t * (t + 3)) >> 1]);  // diag idx
    for (int e = t; e < 4096; e += TPB) {
        int i = e >> 6, jj = e & 63;
        if (i < jj) {
            float a2 = Wb[i * LDW + jj], b2 = Wb[jj * LDW + i];
            Wb[i * LDW + jj] = b2;  Wb[jj * LDW + i] = a2;
        }
    }
    __syncthreads();

    // ---- back-substitution L^T X = L~^T, deferred row scaling: 1 barrier per j (R8) ----
    // Rows stay UNSCALED in LDS; xc is scaled in-register; the final row scale rs[a]
    // is folded into the output phase (outb *= rs[i]*rs[jj]).
    {
        const int c = lane;
        for (int j = 63; j > 0; --j) {
            const int jb = (j * (j + 1)) >> 1;
            float xc = Wb[j * LDW + c] * rs[j];        // row j raw -> scaled in-reg
            for (int i = j - 1 - w; i >= 0; i -= 4) {
                float lji = Ltri[jb + i];              // lane-uniform -> broadcast
                Wb[i * LDW + c] = fmaf(-lji, xc, Wb[i * LDW + c]);
            }
            __syncthreads();
        }
    }

    // ---- upper-tri output: logm[a][b] = rs_a*rs_b * sum_k lw_k W[a][k] W[b][k] ----
    float* __restrict__ outb = out + (size_t)b * NTRI;
    for (int o = t; o < NTRI; o += TPB) {
        int i = (int)((129.0f - sqrtf(16641.0f - 8.0f * (float)o)) * 0.5f);
        while (i > 0 && i * (129 - i) / 2 > o) --i;
        while ((i + 1) * (129 - (i + 1)) / 2 <= o) ++i;
        int jj = i + (o - i * (129 - i) / 2);

        v4f acc4 = {0.f, 0.f, 0.f, 0.f};
        #pragma unroll
        for (int k = 0; k < 16; ++k) {
            v4f lw = *(v4f*)&norms[k << 2];            // lane-uniform -> broadcast
            v4f xa = *(v4f*)&Wb[i  * LDW + (k << 2)];
            v4f xb = *(v4f*)&Wb[jj * LDW + (k << 2)];
            acc4 = v4fma(xa * lw, xb, acc4);
        }
        float ssum = (acc4.x + acc4.y) + (acc4.z + acc4.w);
        outb[o] = ssum * (rs[i] * rs[jj]);
    }
}

extern "C" void kernel_launch(void* const* d_in, const int* in_sizes, int n_in,
                              void* d_out, int out_size, void* d_ws, size_t ws_size,
                              hipStream_t stream) {
    const float* in = (const float*)d_in[0];
    float* out = (float*)d_out;
    int nmat = in_sizes[0] / 4096;    // 8192
    spd_logm_kernel<<<nmat, TPB, 0, stream>>>(in, out);
}

// Round 6
// 2448.120 us; speedup vs baseline: 1.0279x; 1.0279x over previous
//
#include <hip/hip_runtime.h>
#include <cmath>

#define TPB    256
#define SWEEPS 6
#define NTRI   2080      // 64*65/2
#define LDW    68        // row stride (floats): 16B-aligned rows, verified in R6

typedef float v4f __attribute__((ext_vector_type(4)));

// 21 XOR-closed triples {b1, b2, b1^b2} covering masks 1..63 — verified R6.
__constant__ int TB1[21] = {58,53,41,17,34,32,13,26,52,43,37,35,18,36,20,40,44,38,54,47,33};
__constant__ int TH1[21] = { 5, 5, 5, 4, 5, 5, 3, 4, 5, 5, 5, 5, 4, 5, 4, 5, 5, 5, 5, 5, 5};
__constant__ int TB2[21] = { 1, 2, 4, 8,16, 7, 3, 6,12,24,21, 9, 5,10,11,22,19,27,15,30,29};
__constant__ int TH2[21] = { 0, 1, 2, 3, 4, 2, 1, 2, 3, 4, 4, 3, 2, 3, 3, 4, 4, 4, 3, 4, 4};

__device__ __forceinline__ int rfl(int x) { return __builtin_amdgcn_readfirstlane(x); }

template<int CTRL>
__device__ __forceinline__ float dppf(float x) {
    return __int_as_float(__builtin_amdgcn_update_dpp(0, __float_as_int(x), CTRL, 0xf, 0xf, true));
}
// sum across 16-lane DPP row, broadcast to all 16 lanes (verified R6)
__device__ __forceinline__ float red16(float x) {
    x += dppf<0x124>(x);   // row_ror:4
    x += dppf<0x128>(x);   // row_ror:8
    x += dppf<0xB1>(x);    // quad_perm [1,0,3,2]
    x += dppf<0x4E>(x);    // quad_perm [2,3,0,1]
    return x;
}

#if __has_builtin(__builtin_elementwise_fma)
__device__ __forceinline__ v4f v4fma(v4f a, v4f b, v4f c) { return __builtin_elementwise_fma(a, b, c); }
#else
__device__ __forceinline__ v4f v4fma(v4f a, v4f b, v4f c) {
    v4f r; r.x=fmaf(a.x,b.x,c.x); r.y=fmaf(a.y,b.y,c.y); r.z=fmaf(a.z,b.z,c.z); r.w=fmaf(a.w,b.w,c.w); return r;
}
#endif

// fma-chain dot of two v4f (1 mul + 3 fma) — R8
__device__ __forceinline__ float dot4(v4f a, v4f b) {
    float d = a.x * b.x;
    d = fmaf(a.y, b.y, d);
    d = fmaf(a.z, b.z, d);
    d = fmaf(a.w, b.w, d);
    return d;
}

// One Jacobi rotation on register-resident W rows (no VT).
// R10: (a) wave-uniform convergence skip: apq^2 <= 1e-12 * np*nq  (standard
//      one-sided-Jacobi criterion; log-amplification bound <= 1e-4 absmax).
//      (b) angle reformulation t = sign(B)*apq/(|B|+sqrt(apq^2+B^2)) —
//      algebraically identical to the tau form, one fewer transcendental,
//      no division by tiny apq. Returns whether a rotation was applied.
__device__ __forceinline__ bool jrot2(v4f& wp, v4f& wq, float& np, float& nq) {
    float apq = red16(dot4(wp, wq));
    if (__all(apq * apq <= 1e-12f * (np * nq)))
        return false;                              // wave-uniform skip (s_cbranch)
    float B   = (nq - np) * 0.5f;
    float den = fabsf(B) + __builtin_amdgcn_sqrtf(fmaf(apq, apq, B * B));
    float tt  = apq * copysignf(__builtin_amdgcn_rcpf(den), B);
    tt = (fabsf(apq) < 1e-30f) ? 0.f : tt;         // apq==0&&B==0 -> NaN guard (as before)
    float c = __builtin_amdgcn_rsqf(fmaf(tt, tt, 1.f));
    float s = tt * c;
    v4f cc = {c,c,c,c}, ss = {s,s,s,s};
    v4f wa = wp;
    wp = v4fma(cc, wp, -(ss * wq));   // c*wp - s*wq
    wq = v4fma(cc, wq,  (ss * wa));   // c*wq + s*wa
    np = fmaf(-tt, apq, np);
    nq = fmaf( tt, apq, nq);
    return true;
}

__global__ __launch_bounds__(TPB, 6) void spd_logm_kernel(const float* __restrict__ in,
                                                          float* __restrict__ out) {
    // LDS: Wb 17408 B + Ltri 8320 B + norms 256 B + rs 256 B ~= 26.2 KB -> 6 blocks/CU
    __shared__ __align__(16) float Wb[64 * LDW];
    __shared__ __align__(16) float Ltri[NTRI];        // L, row-major lower-tri: [r*(r+1)/2 + c]
    __shared__ __align__(16) float norms[64];         // rsq(diag) -> row norm^2 -> log(lambda)
    __shared__ __align__(16) float rs[64];            // 1/L[j][j] for deferred back-sub scale

    const int b    = blockIdx.x;
    const int t    = threadIdx.x;
    const int lane = t & 63;
    const int w    = rfl(t >> 6);   // wave id (SGPR)
    const int G    = t >> 4;        // 16-lane group 0..15 (one 4-row coset)
    const int u    = t & 15;
    const int u4   = u << 2;

    // ---- load A (b128) ----
    const float4* __restrict__ in4 = (const float4*)(in + (size_t)b * 4096);
    for (int e = t; e < 1024; e += TPB) {
        int row = e >> 4, col = (e & 15) << 2;
        *(float4*)&Wb[row * LDW + col] = in4[e];
    }
    __syncthreads();

    // ---- Cholesky, LDL-style (deferred column scaling): 1 barrier per k  (R8) ----
    for (int k = 0; k < 64; ++k) {
        float dk  = Wb[k * LDW + k];                 // lane-uniform LDS broadcast
        float rdk = __builtin_amdgcn_rcpf(dk);
        float ck  = Wb[lane * LDW + k];              // raw column k
        float ckp = ck * rdk;                        // W[lane][k] / d_k
        for (int i = k + 1 + w; i < 64; i += 4) {
            float aik = __shfl(ck, i, 64);           // W[i][k] raw (uniform idx -> broadcast)
            if (lane > k) Wb[i * LDW + lane] = fmaf(-aik, ckp, Wb[i * LDW + lane]);
        }
        __syncthreads();
    }
    // deferred scaling: L[i][k] = W[i][k] * rsq(d_k); diag -> sqrt(d_k).
    if (t < 64) norms[t] = __builtin_amdgcn_rsqf(Wb[t * LDW + t]);
    __syncthreads();
    for (int e = t; e < 4096; e += TPB) {              // zero strict upper (writes c>r only)
        int r = e >> 6, c = e & 63;
        if (c > r) Wb[r * LDW + c] = 0.f;
    }
    for (int e = t; e < NTRI; e += TPB) {              // scale lower in place + compact copy
        int r = (int)((sqrtf(fmaf(8.f, (float)e, 1.f)) - 1.f) * 0.5f);
        while (r > 0 && r * (r + 1) / 2 > e) --r;
        while ((r + 1) * (r + 2) / 2 <= e) ++r;
        int c = e - r * (r + 1) / 2;
        float v = Wb[r * LDW + c] * norms[c];          // unique (r,c) per e -> race-free
        Wb[r * LDW + c] = v;
        Ltri[e] = v;
    }
    __syncthreads();

    // ---- one-sided Jacobi on rows of L (no VT accumulation) ----
    for (int sweep = 0; sweep < SWEEPS; ++sweep) {
        #pragma unroll
        for (int i = 0; i < 4; ++i) {                  // exact norm^2 refresh
            int r = ((t >> 4) << 2) + i;
            v4f x = *(v4f*)&Wb[r * LDW + u4];
            float nn = red16(dot4(x, x));
            if (u == 0) norms[r] = nn;
        }
        __syncthreads();

        for (int j = 0; j < 21; ++j) {
            const int b1 = TB1[j], h1 = TH1[j], b2 = TB2[j], h2 = TH2[j];
            int m  = (G & ((1 << h2) - 1)) | ((G >> h2) << (h2 + 1));
            int rp = (m & ((1 << h1) - 1)) | ((m >> h1) << (h1 + 1));
            const int z0 = rp, z1 = rp ^ b1, z2 = rp ^ b2, z3 = z1 ^ b2;

            v4f w0 = *(v4f*)&Wb[z0 * LDW + u4];
            v4f w1 = *(v4f*)&Wb[z1 * LDW + u4];
            v4f w2 = *(v4f*)&Wb[z2 * LDW + u4];
            v4f w3 = *(v4f*)&Wb[z3 * LDW + u4];
            float n0 = norms[z0], n1 = norms[z1], n2 = norms[z2], n3 = norms[z3];

            bool any = false;
            any |= jrot2(w0, w1, n0, n1);  any |= jrot2(w2, w3, n2, n3);
            any |= jrot2(w0, w2, n0, n2);  any |= jrot2(w1, w3, n1, n3);
            any |= jrot2(w0, w3, n0, n3);  any |= jrot2(w1, w2, n1, n2);

            if (any) {                                  // wave-uniform: skip stores if converged
                *(v4f*)&Wb[z0 * LDW + u4] = w0;
                *(v4f*)&Wb[z1 * LDW + u4] = w1;
                *(v4f*)&Wb[z2 * LDW + u4] = w2;
                *(v4f*)&Wb[z3 * LDW + u4] = w3;
                if (u == 0) { norms[z0] = n0; norms[z1] = n1; norms[z2] = n2; norms[z3] = n3; }
            }
            __syncthreads();
        }
    }

    // ---- eigenvalues: lambda_k = ||row k||^2 (exact), store log ----
    #pragma unroll
    for (int i = 0; i < 4; ++i) {
        int r = ((t >> 4) << 2) + i;
        v4f x = *(v4f*)&Wb[r * LDW + u4];
        float nn = red16(dot4(x, x));
        if (u == 0) norms[r] = logf(nn);
    }
    __syncthreads();

    // ---- transpose Wb in place (RHS of the solve) + precompute rs[j] = 1/L[j][j] ----
    if (t < 64) rs[t] = __builtin_amdgcn_rcpf(Ltri[(t * (t + 3)) >> 1]);  // diag idx
    for (int e = t; e < 4096; e += TPB) {
        int i = e >> 6, jj = e & 63;
        if (i < jj) {
            float a2 = Wb[i * LDW + jj], b2 = Wb[jj * LDW + i];
            Wb[i * LDW + jj] = b2;  Wb[jj * LDW + i] = a2;
        }
    }
    __syncthreads();

    // ---- back-substitution L^T X = L~^T, deferred row scaling: 1 barrier per j (R8) ----
    {
        const int c = lane;
        for (int j = 63; j > 0; --j) {
            const int jb = (j * (j + 1)) >> 1;
            float xc = Wb[j * LDW + c] * rs[j];        // row j raw -> scaled in-reg
            for (int i = j - 1 - w; i >= 0; i -= 4) {
                float lji = Ltri[jb + i];              // lane-uniform -> broadcast
                Wb[i * LDW + c] = fmaf(-lji, xc, Wb[i * LDW + c]);
            }
            __syncthreads();
        }
    }

    // ---- upper-tri output: logm[a][b] = rs_a*rs_b * sum_k lw_k W[a][k] W[b][k] ----
    float* __restrict__ outb = out + (size_t)b * NTRI;
    for (int o = t; o < NTRI; o += TPB) {
        int i = (int)((129.0f - sqrtf(16641.0f - 8.0f * (float)o)) * 0.5f);
        while (i > 0 && i * (129 - i) / 2 > o) --i;
        while ((i + 1) * (129 - (i + 1)) / 2 <= o) ++i;
        int jj = i + (o - i * (129 - i) / 2);

        v4f acc4 = {0.f, 0.f, 0.f, 0.f};
        #pragma unroll
        for (int k = 0; k < 16; ++k) {
            v4f lw = *(v4f*)&norms[k << 2];            // lane-uniform -> broadcast
            v4f xa = *(v4f*)&Wb[i  * LDW + (k << 2)];
            v4f xb = *(v4f*)&Wb[jj * LDW + (k << 2)];
            acc4 = v4fma(xa * lw, xb, acc4);
        }
        float ssum = (acc4.x + acc4.y) + (acc4.z + acc4.w);
        outb[o] = ssum * (rs[i] * rs[jj]);
    }
}

extern "C" void kernel_launch(void* const* d_in, const int* in_sizes, int n_in,
                              void* d_out, int out_size, void* d_ws, size_t ws_size,
                              hipStream_t stream) {
    const float* in = (const float*)d_in[0];
    float* out = (float*)d_out;
    int nmat = in_sizes[0] / 4096;    // 8192
    spd_logm_kernel<<<nmat, TPB, 0, stream>>>(in, out);
}